// Round 9
// baseline (5550.447 us; speedup 1.0000x reference)
//
#include <hip/hip_runtime.h>
#include <hip/hip_fp16.h>

#define T_LEN 4096
#define START_TAG 14
#define STOP_TAG 15
#define NEG_VAL -10000.0f

typedef unsigned int u32;
typedef unsigned short u16;
typedef unsigned long long u64;
typedef int v4i __attribute__((ext_vector_type(4)));

// ---------- ws layout (bytes) ----------
#define GX_OFF      0u              // __half [4096][2048]  (dir*1024 + d*4 + gate)
#define OUT_OFF     16777216u       // float  [4096][512]
#define LOGITS_OFF  25165824u       // float  [4096]
#define ALPHAS_OFF  25182208u       // float  [4096]
#define FEATS_OFF   25198592u       // float  [4096][16]
#define CMAT_OFF    25460736u       // float  [128][16][16]
#define VIN_OFF     25591808u       // float  [128][16]
#define BP_OFF      25600000u       // u32    [4096][2]
#define BMAP_OFF    25632768u       // u32    [128][16]
#define STAIL_OFF   25640960u       // u32    [128][16]
#define BEST_OFF    25649152u       // u32    [1]

__device__ __forceinline__ u32 packq(int q0, int q1, int q2, int q3) {
  return (u32)(q0 & 255) | ((u32)(q1 & 255) << 8) |
         ((u32)(q2 & 255) << 16) | ((u32)(q3 & 255) << 24);
}

__device__ __forceinline__ float sigm(float x) {
  return __builtin_amdgcn_rcpf(1.f + __expf(-x));
}
__device__ __forceinline__ float tanh_fast(float x) {
  float e = __expf(-2.f * fabsf(x));
  float r = (1.f - e) * __builtin_amdgcn_rcpf(1.f + e);
  return copysignf(r, x);
}

// int8 dot4 with i32 accumulate (v_dot4_i32_i8)
#if defined(__has_builtin)
#  if __has_builtin(__builtin_amdgcn_sdot4)
#    define DOT4(a, b, c) __builtin_amdgcn_sdot4((a), (b), (c), false)
#  endif
#endif
#ifndef DOT4
__device__ __forceinline__ int dot4_emu(int a, int b, int c) {
  #pragma unroll
  for (int j = 0; j < 4; ++j)
    c += (int)((signed char)(a >> (8 * j))) * (int)((signed char)(b >> (8 * j)));
  return c;
}
#  define DOT4(a, b, c) dot4_emu((a), (b), (c))
#endif

// raw workgroup barrier: LDS visibility only (lgkmcnt), NO vmcnt drain --
// keeps the register Gx prefetch in flight across barriers (m201 pattern).
__device__ __forceinline__ void wg_barrier() {
  asm volatile("s_waitcnt lgkmcnt(0)" ::: "memory");
  __builtin_amdgcn_s_barrier();
  __builtin_amdgcn_sched_barrier(0);
}

// ---------------------------------------------------------------------------
__global__ void prep_kernel(float* logits) {
  const int i = threadIdx.x + blockIdx.x * 1024;
  if (i < 4096) logits[i] = 0.f;
}

// ---------------------------------------------------------------------------
// Gx[t][dir*1024 + d*4 + gate] = emb[sentence[t]] . W-row + bih + bhh
__global__ __launch_bounds__(256) void gx_kernel(
    const int* __restrict__ sentence, const float* __restrict__ emb,
    const float* __restrict__ Wih_f, const float* __restrict__ Wih_b,
    const float* __restrict__ bih_f, const float* __restrict__ bhh_f,
    const float* __restrict__ bih_b, const float* __restrict__ bhh_b,
    __half* __restrict__ Gx)
{
  __shared__ float ws[32][260];
  const int r0 = blockIdx.x * 32;
  const int t0 = blockIdx.y * 32;
  const int tid = threadIdx.x;
  {
    const int c4 = (tid & 63) * 4;
    const int rA = tid >> 6;
    #pragma unroll
    for (int p = 0; p < 8; ++p) {
      const int rr = rA + p * 4;
      const int R = r0 + rr;
      const float* src = (R < 1024) ? (Wih_f + (size_t)R * 256 + c4)
                                    : (Wih_b + (size_t)(R - 1024) * 256 + c4);
      *(float4*)&ws[rr][c4] = *(const float4*)src;
    }
  }
  __syncthreads();
  const int ttb = tid >> 4, rgb = tid & 15;
  const int s0r = sentence[t0 + ttb];
  const int s1r = sentence[t0 + ttb + 16];
  const float* x0p = emb + (size_t)s0r * 256;
  const float* x1p = emb + (size_t)s1r * 256;
  float acc00 = 0, acc01 = 0, acc10 = 0, acc11 = 0;
  #pragma unroll 4
  for (int c4 = 0; c4 < 256; c4 += 4) {
    float4 x0 = *(const float4*)(x0p + c4);
    float4 x1 = *(const float4*)(x1p + c4);
    float4 w0 = *(const float4*)&ws[rgb][c4];
    float4 w1 = *(const float4*)&ws[rgb + 16][c4];
    acc00 += x0.x*w0.x + x0.y*w0.y + x0.z*w0.z + x0.w*w0.w;
    acc01 += x0.x*w1.x + x0.y*w1.y + x0.z*w1.z + x0.w*w1.w;
    acc10 += x1.x*w0.x + x1.y*w0.y + x1.z*w0.z + x1.w*w0.w;
    acc11 += x1.x*w1.x + x1.y*w1.y + x1.z*w1.z + x1.w*w1.w;
  }
  #pragma unroll
  for (int ri = 0; ri < 2; ++ri) {
    const int R = r0 + rgb + ri * 16;
    const int dir = R >> 10, grow = R & 1023;
    const int gate = grow >> 8, dd = grow & 255;
    const float bias = dir ? (bih_b[grow] + bhh_b[grow])
                           : (bih_f[grow] + bhh_f[grow]);
    const float a0 = ri ? acc01 : acc00;
    const float a1 = ri ? acc11 : acc10;
    const size_t off = (size_t)dir * 1024 + dd * 4 + gate;
    Gx[(size_t)(t0 + ttb) * 2048 + off]      = __float2half(a0 + bias);
    Gx[(size_t)(t0 + ttb + 16) * 2048 + off] = __float2half(a1 + bias);
  }
}

// ---------------------------------------------------------------------------
// Recurrence v15: in-wave pipe split with ZERO extra LDS traffic (v14's
// failure: 16 extra b128 broadcast reads/wave/step made the step
// LDS-pipe-bound at ~1900 cyc). Key: bfr[4] already holds ALL of h,
// distributed across q-groups (lane (mr,q) has h dwords at 64t+16q+4j).
// So gates g,o run as 4-way-K-split dot4 USING bfr DIRECTLY as B-operand
// (wq quantized in the matching strided layout), reduced with two
// shfl_xor(16/32) along q. Gates i,f stay on MFMA (4 tiles, half of v12).
// The lane with q == mr>>2 holds BOTH the i,f acc rows (4q+{0..3} ∋ mr)
// AND the reduced g,o sums for outputs d0=32w+mr, d1=d0+16 -> the whole
// 2-cell activation is lane-local; no graw, no govt, ONE barrier/step.
// Per-wave LDS/step: 4 bfr reads + 2 byte + 2 u16 writes (= v12 level).
// Same per-row quant max (order-independent fmax + same shfl reduce) ->
// scales identical -> integer gate sums bit-identical to v6..v14.
__global__ __launch_bounds__(512, 2) void lstm_kernel(
    const float* __restrict__ Whh_f, const float* __restrict__ Whh_b,
    const float* __restrict__ h0, const float* __restrict__ c0,
    const __half* __restrict__ Gx, float* __restrict__ out_lstm)
{
  const int dir = blockIdx.x;
  const int tid = threadIdx.x;
  const int w = tid >> 6, l = tid & 63;
  const int mr = l & 15, q = l >> 4;
  const float* Whh = dir ? Whh_b : Whh_f;

  __shared__ __align__(16) char hq8[2][256];    // int8 h, parity buffers
  __shared__ float fsh[512];                    // per-row scales (i,f)
  __shared__ __align__(16) u16 hist[128 * 256]; // 64 KB fp16 h history

  // ---- init A: MFMA fragments, gates i,f ----
  // tile m: gate gx=m&1, half hbt=m>>1; row = gx*256 + 32w + 16*hbt + mr
  v4i wfrag[4][4];
  #pragma unroll
  for (int m = 0; m < 4; ++m) {
    const int row = (m & 1) * 256 + 32 * w + 16 * (m >> 1) + mr;
    const float* wr = Whh + (size_t)row * 256 + 16 * q;
    float mx = 1e-10f;
    #pragma unroll
    for (int t = 0; t < 4; ++t) {
      #pragma unroll
      for (int c4 = 0; c4 < 4; ++c4) {
        float4 f = *(const float4*)(wr + 64 * t + 4 * c4);
        mx = fmaxf(mx, fmaxf(fmaxf(fabsf(f.x), fabsf(f.y)),
                             fmaxf(fabsf(f.z), fabsf(f.w))));
      }
    }
    mx = fmaxf(mx, __shfl_xor(mx, 16));
    mx = fmaxf(mx, __shfl_xor(mx, 32));
    const float qs = 127.f / mx;
    if (q == 0) fsh[row] = mx * (1.f / (127.f * 32.f));  // w-scale * h-scale
    #pragma unroll
    for (int t = 0; t < 4; ++t) {
      u32 pk[4];
      #pragma unroll
      for (int c4 = 0; c4 < 4; ++c4) {
        float4 f = *(const float4*)(wr + 64 * t + 4 * c4);
        pk[c4] = packq((int)rintf(f.x * qs), (int)rintf(f.y * qs),
                       (int)rintf(f.z * qs), (int)rintf(f.w * qs));
      }
      v4i v; v[0] = (int)pk[0]; v[1] = (int)pk[1]; v[2] = (int)pk[2]; v[3] = (int)pk[3];
      wfrag[m][t] = v;
    }
  }

  // ---- init B: dot4 rows for g,o in bfr-matching strided layout ----
  // row j: gate gj=j>>1 (0=g,1=o), output dm = mr + 16*(j&1);
  // wq[j][4t+jj] = quantized W[(2+gj)*256 + 32w+dm][64t + 16q + 4jj .. +3]
  int wq[4][16];
  float fsgo[4];
  #pragma unroll
  for (int j = 0; j < 4; ++j) {
    const int gj = j >> 1, dmj = mr + 16 * (j & 1);
    const float* wr = Whh + (size_t)((2 + gj) * 256 + 32 * w + dmj) * 256 + 16 * q;
    float mx = 1e-10f;
    #pragma unroll
    for (int t = 0; t < 4; ++t) {
      #pragma unroll
      for (int jj = 0; jj < 4; ++jj) {
        float4 f = *(const float4*)(wr + 64 * t + 4 * jj);
        mx = fmaxf(mx, fmaxf(fmaxf(fabsf(f.x), fabsf(f.y)),
                             fmaxf(fabsf(f.z), fabsf(f.w))));
      }
    }
    mx = fmaxf(mx, __shfl_xor(mx, 16));      // full-row max across q groups
    mx = fmaxf(mx, __shfl_xor(mx, 32));
    const float qs = 127.f / mx;
    fsgo[j] = mx * (1.f / (127.f * 32.f));
    #pragma unroll
    for (int t = 0; t < 4; ++t) {
      #pragma unroll
      for (int jj = 0; jj < 4; ++jj) {
        float4 f = *(const float4*)(wr + 64 * t + 4 * jj);
        wq[j][4 * t + jj] = (int)packq((int)rintf(f.x * qs), (int)rintf(f.y * qs),
                                       (int)rintf(f.z * qs), (int)rintf(f.w * qs));
      }
    }
  }

  // act lane: unique lane holding both i,f acc rows and g,o sums for
  // d0 = 32w + mr, d1 = d0 + 16 -> q == mr>>2.
  const bool is_act = (q == (mr >> 2));
  const int d0 = 32 * w + mr, d1 = d0 + 16;
  float creg0 = 0.f, creg1 = 0.f;
  if (is_act) {
    creg0 = c0[dir * 256 + d0];
    creg1 = c0[dir * 256 + d1];
    float hv0 = h0[dir * 256 + d0];
    float hv1 = h0[dir * 256 + d1];
    hq8[0][d0] = (char)max(-127, min(127, (int)rintf(hv0 * 32.f)));
    hq8[0][d1] = (char)max(-127, min(127, (int)rintf(hv1 * 32.f)));
  }
  __syncthreads();                      // init: full drain once

  const float fi0 = fsh[d0], ff0 = fsh[256 + d0];
  const float fi1 = fsh[d1], ff1 = fsh[256 + d1];
  const uint2* Gx2 = (const uint2*)Gx;
  uint2 ga0[4], ga1[4];
  #pragma unroll
  for (int k = 0; k < 4; ++k) {
    const int t = dir ? (T_LEN - 1 - k) : k;
    ga0[k] = Gx2[(size_t)t * 512 + dir * 256 + d0];
    ga1[k] = Gx2[(size_t)t * 512 + dir * 256 + d1];
  }

  const int r3 = mr & 3;                // element selector within acc row quad

  for (int sb = 0; sb < T_LEN; sb += 4) {
    uint2 gn0[4], gn1[4];
    const bool more = (sb + 4) < T_LEN;
    if (more) {          // prefetch next batch; rides across barriers
      #pragma unroll
      for (int k = 0; k < 4; ++k) {
        const int t2 = sb + 4 + k;
        const int t = dir ? (T_LEN - 1 - t2) : t2;
        gn0[k] = Gx2[(size_t)t * 512 + dir * 256 + d0];
        gn1[k] = Gx2[(size_t)t * 512 + dir * 256 + d1];
      }
    }
    #pragma unroll
    for (int k = 0; k < 4; ++k) {
      const int s = sb + k;
      const char* hc = hq8[s & 1];
      v4i bfr[4];
      #pragma unroll
      for (int t = 0; t < 4; ++t)
        bfr[t] = *(const v4i*)(hc + 64 * t + 16 * q);
      // ---- MFMA: gates i,f (matrix pipe) ----
      v4i acc[4];
      #pragma unroll
      for (int m = 0; m < 4; ++m) {
        v4i a; a[0] = 0; a[1] = 0; a[2] = 0; a[3] = 0;
        a = __builtin_amdgcn_mfma_i32_16x16x64_i8(wfrag[m][0], bfr[0], a, 0, 0, 0);
        a = __builtin_amdgcn_mfma_i32_16x16x64_i8(wfrag[m][1], bfr[1], a, 0, 0, 0);
        a = __builtin_amdgcn_mfma_i32_16x16x64_i8(wfrag[m][2], bfr[2], a, 0, 0, 0);
        a = __builtin_amdgcn_mfma_i32_16x16x64_i8(wfrag[m][3], bfr[3], a, 0, 0, 0);
        acc[m] = a;
      }
      // ---- dot4: gates g,o from bfr registers (VALU pipe, no LDS) ----
      int p0 = 0, p1 = 0, p2 = 0, p3 = 0;
      #pragma unroll
      for (int t = 0; t < 4; ++t) {
        #pragma unroll
        for (int jj = 0; jj < 4; ++jj) {
          const int hw = bfr[t][jj];
          p0 = DOT4(wq[0][4 * t + jj], hw, p0);
          p1 = DOT4(wq[1][4 * t + jj], hw, p1);
          p2 = DOT4(wq[2][4 * t + jj], hw, p2);
          p3 = DOT4(wq[3][4 * t + jj], hw, p3);
        }
      }
      p0 += __shfl_xor(p0, 16); p0 += __shfl_xor(p0, 32);
      p1 += __shfl_xor(p1, 16); p1 += __shfl_xor(p1, 32);
      p2 += __shfl_xor(p2, 16); p2 += __shfl_xor(p2, 32);
      p3 += __shfl_xor(p3, 16); p3 += __shfl_xor(p3, 32);
      // ---- in-register i,f extraction (element r3 of each tile) ----
      int e0, e1, e2, e3;
      {
        int lo, hi;
        lo = (r3 & 1) ? acc[0][1] : acc[0][0];
        hi = (r3 & 1) ? acc[0][3] : acc[0][2];
        e0 = (r3 & 2) ? hi : lo;
        lo = (r3 & 1) ? acc[1][1] : acc[1][0];
        hi = (r3 & 1) ? acc[1][3] : acc[1][2];
        e1 = (r3 & 2) ? hi : lo;
        lo = (r3 & 1) ? acc[2][1] : acc[2][0];
        hi = (r3 & 1) ? acc[2][3] : acc[2][2];
        e2 = (r3 & 2) ? hi : lo;
        lo = (r3 & 1) ? acc[3][1] : acc[3][0];
        hi = (r3 & 1) ? acc[3][3] : acc[3][2];
        e3 = (r3 & 2) ? hi : lo;
      }
      // ---- 2-cell activation on act lanes ----
      if (is_act) {
        const float xi0 = (float)e0 * fi0 + __half2float(__ushort_as_half((u16)(ga0[k].x & 0xffff)));
        const float xf0 = (float)e1 * ff0 + __half2float(__ushort_as_half((u16)(ga0[k].x >> 16)));
        const float xg0 = (float)p0 * fsgo[0] + __half2float(__ushort_as_half((u16)(ga0[k].y & 0xffff)));
        const float xo0 = (float)p2 * fsgo[2] + __half2float(__ushort_as_half((u16)(ga0[k].y >> 16)));
        const float xi1 = (float)e2 * fi1 + __half2float(__ushort_as_half((u16)(ga1[k].x & 0xffff)));
        const float xf1 = (float)e3 * ff1 + __half2float(__ushort_as_half((u16)(ga1[k].x >> 16)));
        const float xg1 = (float)p1 * fsgo[1] + __half2float(__ushort_as_half((u16)(ga1[k].y & 0xffff)));
        const float xo1 = (float)p3 * fsgo[3] + __half2float(__ushort_as_half((u16)(ga1[k].y >> 16)));
        const float iv0 = sigm(xi0), fv0 = sigm(xf0);
        const float gv0 = tanh_fast(xg0), ov0 = sigm(xo0);
        const float iv1 = sigm(xi1), fv1 = sigm(xf1);
        const float gv1 = tanh_fast(xg1), ov1 = sigm(xo1);
        creg0 = __builtin_fmaf(fv0, creg0, iv0 * gv0);
        creg1 = __builtin_fmaf(fv1, creg1, iv1 * gv1);
        const float h0v = ov0 * tanh_fast(creg0);
        const float h1v = ov1 * tanh_fast(creg1);
        hq8[(s + 1) & 1][d0] = (char)max(-127, min(127, (int)rintf(h0v * 32.f)));
        hq8[(s + 1) & 1][d1] = (char)max(-127, min(127, (int)rintf(h1v * 32.f)));
        hist[(s & 127) * 256 + d0] = __half_as_ushort(__float2half(h0v));
        hist[(s & 127) * 256 + d1] = __half_as_ushort(__float2half(h1v));
      }
      wg_barrier();                     // ONE barrier/step: h(s+1) published
    }
    if ((sb & 127) == 124) {    // flush fp16 history -> out_lstm
      const int sbase = sb - 124;
      #pragma unroll 4
      for (int i = 0; i < 16; ++i) {
        const int idx = tid + i * 512;           // uint2 index into hist
        const int step = idx >> 6, dc = (idx & 63) * 4;
        const int tt = sbase + step;
        const int tg = dir ? (T_LEN - 1 - tt) : tt;
        uint2 hv = ((const uint2*)hist)[idx];
        float4 ov4;
        ov4.x = __half2float(__ushort_as_half((u16)(hv.x & 0xffff)));
        ov4.y = __half2float(__ushort_as_half((u16)(hv.x >> 16)));
        ov4.z = __half2float(__ushort_as_half((u16)(hv.y & 0xffff)));
        ov4.w = __half2float(__ushort_as_half((u16)(hv.y >> 16)));
        *(float4*)&out_lstm[(size_t)tg * 512 + dir * 256 + dc] = ov4;
      }
      wg_barrier();
    }
    if (more) {
      #pragma unroll
      for (int k = 0; k < 4; ++k) { ga0[k] = gn0[k]; ga1[k] = gn1[k]; }
    }
  }
}

// ---------------------------------------------------------------------------
__global__ __launch_bounds__(256) void attn_kernel(
    const float* __restrict__ out_lstm, const float* __restrict__ w_omega,
    const float* __restrict__ u_omega, float* __restrict__ logits)
{
  __shared__ float bst[32][132];
  const int c0 = blockIdx.x * 32;
  const int t0 = blockIdx.y * 32;
  const int tid = threadIdx.x;
  const int ttb = tid >> 4, cgb = tid & 15;
  const float* a0p = out_lstm + (size_t)(t0 + ttb) * 512;
  const float* a1p = out_lstm + (size_t)(t0 + ttb + 16) * 512;
  float acc00 = 0, acc01 = 0, acc10 = 0, acc11 = 0;
  for (int kh = 0; kh < 4; ++kh) {
    __syncthreads();
    {
      const int cc = tid & 31;
      const int kA = tid >> 5;
      #pragma unroll
      for (int p = 0; p < 16; ++p) {
        const int kkx = kA + p * 8;
        bst[cc][kkx] = w_omega[(size_t)(kh * 128 + kkx) * 512 + c0 + cc];
      }
    }
    __syncthreads();
    #pragma unroll 4
    for (int k4 = 0; k4 < 128; k4 += 4) {
      float4 a0 = *(const float4*)(a0p + kh * 128 + k4);
      float4 a1 = *(const float4*)(a1p + kh * 128 + k4);
      float4 b0 = *(const float4*)&bst[cgb][k4];
      float4 b1 = *(const float4*)&bst[cgb + 16][k4];
      acc00 += a0.x*b0.x + a0.y*b0.y + a0.z*b0.z + a0.w*b0.w;
      acc01 += a0.x*b1.x + a0.y*b1.y + a0.z*b1.z + a0.w*b1.w;
      acc10 += a1.x*b0.x + a1.y*b0.y + a1.z*b0.z + a1.w*b0.w;
      acc11 += a1.x*b1.x + a1.y*b1.y + a1.z*b1.z + a1.w*b1.w;
    }
  }
  const float u0 = u_omega[c0 + cgb], u1 = u_omega[c0 + 16 + cgb];
  float s0 = tanh_fast(acc00) * u0 + tanh_fast(acc01) * u1;
  float s1 = tanh_fast(acc10) * u0 + tanh_fast(acc11) * u1;
  #pragma unroll
  for (int msk = 1; msk < 16; msk <<= 1) {
    s0 += __shfl_xor(s0, msk);
    s1 += __shfl_xor(s1, msk);
  }
  if (cgb == 0) {
    atomicAdd(&logits[t0 + ttb], s0);
    atomicAdd(&logits[t0 + ttb + 16], s1);
  }
}

// ---------------------------------------------------------------------------
__global__ __launch_bounds__(1024) void softmax_kernel(
    const float* __restrict__ logits, float* __restrict__ alphas)
{
  __shared__ float red[1024];
  const int tid = threadIdx.x;
  float l0 = logits[tid], l1 = logits[1024 + tid];
  float l2 = logits[2048 + tid], l3 = logits[3072 + tid];
  red[tid] = fmaxf(fmaxf(l0, l1), fmaxf(l2, l3));
  __syncthreads();
  for (int s = 512; s > 0; s >>= 1) {
    if (tid < s) red[tid] = fmaxf(red[tid], red[tid + s]);
    __syncthreads();
  }
  const float gm = red[0];
  __syncthreads();
  float e0 = __expf(l0 - gm), e1 = __expf(l1 - gm);
  float e2 = __expf(l2 - gm), e3 = __expf(l3 - gm);
  red[tid] = e0 + e1 + e2 + e3;
  __syncthreads();
  for (int s = 512; s > 0; s >>= 1) {
    if (tid < s) red[tid] += red[tid + s];
    __syncthreads();
  }
  const float inv = 1.0f / red[0];
  alphas[tid] = e0 * inv; alphas[1024 + tid] = e1 * inv;
  alphas[2048 + tid] = e2 * inv; alphas[3072 + tid] = e3 * inv;
}

// ---------------------------------------------------------------------------
__global__ __launch_bounds__(256) void feats_kernel(
    const float* __restrict__ out_lstm, const float* __restrict__ W_tag,
    const float* __restrict__ b_tag, const float* __restrict__ alphas,
    float* __restrict__ feats)
{
  __shared__ float wt[16][516];
  const int t0 = blockIdx.x * 16;
  const int tid = threadIdx.x;
  {
    const int k4 = (tid & 127) * 4;
    const int gA = tid >> 7;
    #pragma unroll
    for (int p = 0; p < 8; ++p) {
      const int tg = gA + p * 2;
      *(float4*)&wt[tg][k4] = *(const float4*)(W_tag + (size_t)tg * 512 + k4);
    }
  }
  __syncthreads();
  const int tt = tid >> 4, tg = tid & 15;
  const float* ap = out_lstm + (size_t)(t0 + tt) * 512;
  float acc = 0.f;
  #pragma unroll 4
  for (int k4 = 0; k4 < 512; k4 += 4) {
    float4 a = *(const float4*)(ap + k4);
    float4 b = *(const float4*)&wt[tg][k4];
    acc += a.x*b.x + a.y*b.y + a.z*b.z + a.w*b.w;
  }
  feats[(size_t)(t0 + tt) * 16 + tg] = acc * alphas[t0 + tt] + b_tag[tg];
}

// ---------------------------------------------------------------------------
__global__ __launch_bounds__(256) void vit_block_mats(
    const float* __restrict__ feats, const float* __restrict__ trans,
    float* __restrict__ Cmat)
{
  __shared__ float C[2][16][17];
  const int b = blockIdx.x;
  const int tid = threadIdx.x;
  const int n = tid >> 4, p = tid & 15;
  float tr[16];
  #pragma unroll
  for (int k = 0; k < 16; ++k) tr[k] = trans[n * 16 + k];
  const int t0 = b * 32;
  C[0][n][p] = tr[p] + feats[t0 * 16 + n];
  float fnext = feats[(t0 + 1) * 16 + n];
  __syncthreads();
  for (int s = 1; s < 32; ++s) {
    const float ft = fnext;
    if (s + 1 < 32) fnext = feats[(t0 + s + 1) * 16 + n];
    const int pr = (s - 1) & 1, cu = s & 1;
    float m = tr[0] + C[pr][0][p];
    #pragma unroll
    for (int k = 1; k < 16; ++k) m = fmaxf(m, tr[k] + C[pr][k][p]);
    C[cu][n][p] = m + ft;
    __syncthreads();
  }
  Cmat[b * 256 + n * 16 + p] = C[1][n][p];
}

__global__ __launch_bounds__(64) void vit_scan(
    const float* __restrict__ Cmat, const float* __restrict__ trans,
    float* __restrict__ v_in, float* __restrict__ d_out, u32* __restrict__ best_ws)
{
  const int l = threadIdx.x;
  const int n = l & 15, pg = l >> 4;
  float v = (n == START_TAG) ? 0.f : NEG_VAL;
  for (int b = 0; b < 128; ++b) {
    if (pg == 0) v_in[b * 16 + n] = v;
    float4 c4 = *(const float4*)&Cmat[b * 256 + n * 16 + pg * 4];
    float cand = c4.x + __shfl(v, pg * 4 + 0);
    cand = fmaxf(cand, c4.y + __shfl(v, pg * 4 + 1));
    cand = fmaxf(cand, c4.z + __shfl(v, pg * 4 + 2));
    cand = fmaxf(cand, c4.w + __shfl(v, pg * 4 + 3));
    cand = fmaxf(cand, __shfl_xor(cand, 16));
    cand = fmaxf(cand, __shfl_xor(cand, 32));
    v = cand;
  }
  float term = v + trans[STOP_TAG * 16 + n];
  int mi = n;
  #pragma unroll
  for (int msk = 1; msk < 16; msk <<= 1) {
    float om = __shfl_xor(term, msk); int omi = __shfl_xor(mi, msk);
    if (om > term || (om == term && omi < mi)) { term = om; mi = omi; }
  }
  if (l == 0) { d_out[0] = term; *best_ws = (u32)mi; }
}

__global__ __launch_bounds__(64) void vit_bp(
    const float* __restrict__ feats, const float* __restrict__ trans,
    const float* __restrict__ v_in, u32* __restrict__ bp)
{
  const int b = blockIdx.x;
  const int l = threadIdx.x;
  const int n = l & 15, pg = l >> 4;
  const float4 tr4 = *(const float4*)&trans[n * 16 + pg * 4];
  float v = v_in[b * 16 + n];
  const int t0 = b * 32;
  float fcur = feats[t0 * 16 + n];
  for (int s = 0; s < 32; ++s) {
    const int t = t0 + s;
    float fnext = (s + 1 < 32) ? feats[(t + 1) * 16 + n] : 0.f;
    float f0 = __shfl(v, pg * 4 + 0), f1 = __shfl(v, pg * 4 + 1);
    float f2 = __shfl(v, pg * 4 + 2), f3 = __shfl(v, pg * 4 + 3);
    float m = f0 + tr4.x; int mi = pg * 4;
    float c;
    c = f1 + tr4.y; if (c > m) { m = c; mi = pg * 4 + 1; }
    c = f2 + tr4.z; if (c > m) { m = c; mi = pg * 4 + 2; }
    c = f3 + tr4.w; if (c > m) { m = c; mi = pg * 4 + 3; }
    float om; int omi;
    om = __shfl_xor(m, 16); omi = __shfl_xor(mi, 16);
    if (om > m || (om == m && omi < mi)) { m = om; mi = omi; }
    om = __shfl_xor(m, 32); omi = __shfl_xor(mi, 32);
    if (om > m || (om == m && omi < mi)) { m = om; mi = omi; }
    u32 w = (l < 16) ? ((u32)mi << ((n & 7) * 4)) : 0u;
    w |= __shfl_xor(w, 1); w |= __shfl_xor(w, 2); w |= __shfl_xor(w, 4);
    if (l == 0) bp[t * 2] = w;
    if (l == 8) bp[t * 2 + 1] = w;
    v = m + fcur;
    fcur = fnext;
  }
}

__global__ __launch_bounds__(64) void vit_bmap(
    const u32* __restrict__ bp, u32* __restrict__ Bmap)
{
  const int b = blockIdx.x;
  const int l = threadIdx.x;
  if (l >= 16) return;
  int t = b * 32 + 31;
  u32 lo = bp[t * 2], hi = bp[t * 2 + 1];
  int A = (int)(((l < 8 ? lo : hi) >> ((l & 7) * 4)) & 15u);
  for (t = b * 32 + 30; t >= b * 32; --t) {
    lo = bp[t * 2]; hi = bp[t * 2 + 1];
    A = (int)(((A < 8 ? lo : hi) >> ((A & 7) * 4)) & 15u);
  }
  Bmap[b * 16 + l] = (u32)A;
}

__global__ __launch_bounds__(64) void vit_suffix(
    const u32* __restrict__ Bmap, u32* __restrict__ Stail)
{
  __shared__ u32 bm[2048];
  const int l = threadIdx.x;
  for (int i = l; i < 2048; i += 64) bm[i] = Bmap[i];
  __syncthreads();
  if (l < 16) {
    int S = l;
    for (int b = 127; b >= 0; --b) {
      Stail[b * 16 + l] = (u32)S;
      S = (int)bm[b * 16 + S];
    }
  }
}

__global__ __launch_bounds__(64) void vit_emit(
    const u32* __restrict__ bp, const u32* __restrict__ Stail,
    const u32* __restrict__ best_ws, float* __restrict__ d_out)
{
  const int b = blockIdx.x;
  const int l = threadIdx.x;
  const int best = (int)*best_ws;
  int A = (l < 16) ? (int)Stail[b * 16 + l] : 0;
  for (int s = 31; s >= 0; --s) {
    const int t = b * 32 + s;
    const int pv = __shfl(A, best);
    if (l == 0) d_out[1 + t] = (float)pv;
    if (s > 0) {
      const u32 lo = bp[t * 2], hi = bp[t * 2 + 1];
      A = (int)(((A < 8 ? lo : hi) >> ((A & 7) * 4)) & 15u);
    }
  }
}

// ---------------------------------------------------------------------------
extern "C" void kernel_launch(void* const* d_in, const int* in_sizes, int n_in,
                              void* d_out, int out_size, void* d_ws, size_t ws_size,
                              hipStream_t stream)
{
  const int*   sentence = (const int*)  d_in[0];
  const float* emb      = (const float*)d_in[1];
  const float* Wih_f    = (const float*)d_in[2];
  const float* Whh_f    = (const float*)d_in[3];
  const float* bih_f    = (const float*)d_in[4];
  const float* bhh_f    = (const float*)d_in[5];
  const float* Wih_b    = (const float*)d_in[6];
  const float* Whh_b    = (const float*)d_in[7];
  const float* bih_b    = (const float*)d_in[8];
  const float* bhh_b    = (const float*)d_in[9];
  const float* h0       = (const float*)d_in[10];
  const float* c0       = (const float*)d_in[11];
  const float* w_omega  = (const float*)d_in[12];
  const float* u_omega  = (const float*)d_in[13];
  const float* W_tag    = (const float*)d_in[14];
  const float* b_tag    = (const float*)d_in[15];
  const float* trans    = (const float*)d_in[16];

  char* ws = (char*)d_ws;
  __half* Gx      = (__half*)(ws + GX_OFF);
  float* out_lstm = (float*)(ws + OUT_OFF);
  float* logits   = (float*)(ws + LOGITS_OFF);
  float* alphas   = (float*)(ws + ALPHAS_OFF);
  float* feats    = (float*)(ws + FEATS_OFF);
  float* Cmat     = (float*)(ws + CMAT_OFF);
  float* v_in     = (float*)(ws + VIN_OFF);
  u32*   bp       = (u32*)  (ws + BP_OFF);
  u32*   Bmap     = (u32*)  (ws + BMAP_OFF);
  u32*   Stail    = (u32*)  (ws + STAIL_OFF);
  u32*   best_ws  = (u32*)  (ws + BEST_OFF);
  float* out      = (float*)d_out;

  hipLaunchKernelGGL(prep_kernel, dim3(4), dim3(1024), 0, stream, logits);
  hipLaunchKernelGGL(gx_kernel, dim3(64, 128), dim3(256), 0, stream,
                     sentence, emb, Wih_f, Wih_b, bih_f, bhh_f, bih_b, bhh_b, Gx);
  hipLaunchKernelGGL(lstm_kernel, dim3(2), dim3(512), 0, stream,
                     Whh_f, Whh_b, h0, c0, Gx, out_lstm);
  hipLaunchKernelGGL(attn_kernel, dim3(16, 128), dim3(256), 0, stream,
                     out_lstm, w_omega, u_omega, logits);
  hipLaunchKernelGGL(softmax_kernel, dim3(1), dim3(1024), 0, stream, logits, alphas);
  hipLaunchKernelGGL(feats_kernel, dim3(256), dim3(256), 0, stream,
                     out_lstm, W_tag, b_tag, alphas, feats);
  hipLaunchKernelGGL(vit_block_mats, dim3(128), dim3(256), 0, stream,
                     feats, trans, Cmat);
  hipLaunchKernelGGL(vit_scan, dim3(1), dim3(64), 0, stream,
                     Cmat, trans, v_in, out, best_ws);
  hipLaunchKernelGGL(vit_bp, dim3(128), dim3(64), 0, stream,
                     feats, trans, v_in, bp);
  hipLaunchKernelGGL(vit_bmap, dim3(128), dim3(64), 0, stream, bp, Bmap);
  hipLaunchKernelGGL(vit_suffix, dim3(1), dim3(64), 0, stream, Bmap, Stail);
  hipLaunchKernelGGL(vit_emit, dim3(128), dim3(64), 0, stream,
                     bp, Stail, best_ws, out);
}

// Round 10
// 3536.486 us; speedup vs baseline: 1.5695x; 1.5695x over previous
//
#include <hip/hip_runtime.h>
#include <hip/hip_fp16.h>

#define T_LEN 4096
#define START_TAG 14
#define STOP_TAG 15
#define NEG_VAL -10000.0f

typedef unsigned int u32;
typedef unsigned short u16;
typedef unsigned long long u64;
typedef int v4i __attribute__((ext_vector_type(4)));

// ---------- ws layout (bytes) ----------
#define GX_OFF      0u              // __half [4096][2048]  (dir*1024 + d*4 + gate)
#define OUT_OFF     16777216u       // float  [4096][512]
#define LOGITS_OFF  25165824u       // float  [4096]
#define ALPHAS_OFF  25182208u       // float  [4096]
#define FEATS_OFF   25198592u       // float  [4096][16]
#define CMAT_OFF    25460736u       // float  [128][16][16]
#define VIN_OFF     25591808u       // float  [128][16]
#define BP_OFF      25600000u       // u32    [4096][2]
#define BMAP_OFF    25632768u       // u32    [128][16]
#define STAIL_OFF   25640960u       // u32    [128][16]
#define BEST_OFF    25649152u       // u32    [1]

__device__ __forceinline__ u32 packq(int q0, int q1, int q2, int q3) {
  return (u32)(q0 & 255) | ((u32)(q1 & 255) << 8) |
         ((u32)(q2 & 255) << 16) | ((u32)(q3 & 255) << 24);
}

__device__ __forceinline__ float sigm(float x) {
  return __builtin_amdgcn_rcpf(1.f + __expf(-x));
}
__device__ __forceinline__ float tanh_fast(float x) {
  float e = __expf(-2.f * fabsf(x));
  float r = (1.f - e) * __builtin_amdgcn_rcpf(1.f + e);
  return copysignf(r, x);
}

// raw workgroup barrier: LDS visibility only (lgkmcnt), NO vmcnt drain --
// keeps the register Gx prefetch and the out_lstm stores in flight
// across barriers (m201 pattern).
__device__ __forceinline__ void wg_barrier() {
  asm volatile("s_waitcnt lgkmcnt(0)" ::: "memory");
  __builtin_amdgcn_s_barrier();
  __builtin_amdgcn_sched_barrier(0);
}

// ---------------------------------------------------------------------------
__global__ void prep_kernel(float* logits) {
  const int i = threadIdx.x + blockIdx.x * 1024;
  if (i < 4096) logits[i] = 0.f;
}

// ---------------------------------------------------------------------------
// Gx[t][dir*1024 + d*4 + gate] = emb[sentence[t]] . W-row + bih + bhh
__global__ __launch_bounds__(256) void gx_kernel(
    const int* __restrict__ sentence, const float* __restrict__ emb,
    const float* __restrict__ Wih_f, const float* __restrict__ Wih_b,
    const float* __restrict__ bih_f, const float* __restrict__ bhh_f,
    const float* __restrict__ bih_b, const float* __restrict__ bhh_b,
    __half* __restrict__ Gx)
{
  __shared__ float ws[32][260];
  const int r0 = blockIdx.x * 32;
  const int t0 = blockIdx.y * 32;
  const int tid = threadIdx.x;
  {
    const int c4 = (tid & 63) * 4;
    const int rA = tid >> 6;
    #pragma unroll
    for (int p = 0; p < 8; ++p) {
      const int rr = rA + p * 4;
      const int R = r0 + rr;
      const float* src = (R < 1024) ? (Wih_f + (size_t)R * 256 + c4)
                                    : (Wih_b + (size_t)(R - 1024) * 256 + c4);
      *(float4*)&ws[rr][c4] = *(const float4*)src;
    }
  }
  __syncthreads();
  const int ttb = tid >> 4, rgb = tid & 15;
  const int s0r = sentence[t0 + ttb];
  const int s1r = sentence[t0 + ttb + 16];
  const float* x0p = emb + (size_t)s0r * 256;
  const float* x1p = emb + (size_t)s1r * 256;
  float acc00 = 0, acc01 = 0, acc10 = 0, acc11 = 0;
  #pragma unroll 4
  for (int c4 = 0; c4 < 256; c4 += 4) {
    float4 x0 = *(const float4*)(x0p + c4);
    float4 x1 = *(const float4*)(x1p + c4);
    float4 w0 = *(const float4*)&ws[rgb][c4];
    float4 w1 = *(const float4*)&ws[rgb + 16][c4];
    acc00 += x0.x*w0.x + x0.y*w0.y + x0.z*w0.z + x0.w*w0.w;
    acc01 += x0.x*w1.x + x0.y*w1.y + x0.z*w1.z + x0.w*w1.w;
    acc10 += x1.x*w0.x + x1.y*w0.y + x1.z*w0.z + x1.w*w0.w;
    acc11 += x1.x*w1.x + x1.y*w1.y + x1.z*w1.z + x1.w*w1.w;
  }
  #pragma unroll
  for (int ri = 0; ri < 2; ++ri) {
    const int R = r0 + rgb + ri * 16;
    const int dir = R >> 10, grow = R & 1023;
    const int gate = grow >> 8, dd = grow & 255;
    const float bias = dir ? (bih_b[grow] + bhh_b[grow])
                           : (bih_f[grow] + bhh_f[grow]);
    const float a0 = ri ? acc01 : acc00;
    const float a1 = ri ? acc11 : acc10;
    const size_t off = (size_t)dir * 1024 + dd * 4 + gate;
    Gx[(size_t)(t0 + ttb) * 2048 + off]      = __float2half(a0 + bias);
    Gx[(size_t)(t0 + ttb + 16) * 2048 + off] = __float2half(a1 + bias);
  }
}

// ---------------------------------------------------------------------------
// Recurrence v16 = v12 (best: 3160 us) minus the hist path. v12's skeleton:
// gate sums never touch LDS (all 16 MFMA C-columns are identical since the
// B-fragment has no mr-dependence -> every lane holds C rows 4q+{0..3} in
// registers; 7-cndmask select per gate extracts them). ONE barrier/step.
// v16 change: h goes STRAIGHT to out_lstm as a fire-and-forget global store
// (act lanes of a wave cover a contiguous 128B segment -> coalesced; raw
// barrier never drains vmcnt so stores ride). This removes 2 hist u16
// LDS-writes/step from the pre-barrier lgkmcnt(0) drain, the 128-step
// flush phase, and its extra barrier. Stored value keeps the fp16
// round-trip (__half2float(__float2half(h))) -> output bit-identical to
// v12. Hybrid pipe-splits (v13/v14/v15) all regressed -- coordination
// overhead (cross-wave barriers / LDS-pipe saturation / shfl serialization)
// exceeds the ~650 cyc of recoverable matrix-pipe time; not pursued.
__global__ __launch_bounds__(512, 2) void lstm_kernel(
    const float* __restrict__ Whh_f, const float* __restrict__ Whh_b,
    const float* __restrict__ h0, const float* __restrict__ c0,
    const __half* __restrict__ Gx, float* __restrict__ out_lstm)
{
  const int dir = blockIdx.x;
  const int tid = threadIdx.x;
  const int w = tid >> 6, l = tid & 63;
  const int mr = l & 15, q = l >> 4;
  const float* Whh = dir ? Whh_b : Whh_f;

  __shared__ __align__(16) char hq8[2][256];    // int8 h, parity buffers
  __shared__ float fsh[1024];                   // per-row scales (all gates)

  // ---- init: wave w, M-tile m -> gate g=m&3, half hb=m>>2,
  //      global row = g*256 + 32w + 16*hb + mr ----
  v4i wfrag[8][4];
  #pragma unroll
  for (int m = 0; m < 8; ++m) {
    const int row = (m & 3) * 256 + 32 * w + 16 * (m >> 2) + mr;
    const float* wr = Whh + (size_t)row * 256 + 16 * q;
    float mx = 1e-10f;
    #pragma unroll
    for (int t = 0; t < 4; ++t) {
      #pragma unroll
      for (int c4 = 0; c4 < 4; ++c4) {
        float4 f = *(const float4*)(wr + 64 * t + 4 * c4);
        mx = fmaxf(mx, fmaxf(fmaxf(fabsf(f.x), fabsf(f.y)),
                             fmaxf(fabsf(f.z), fabsf(f.w))));
      }
    }
    mx = fmaxf(mx, __shfl_xor(mx, 16));
    mx = fmaxf(mx, __shfl_xor(mx, 32));
    const float qs = 127.f / mx;
    if (q == 0) fsh[row] = mx * (1.f / (127.f * 32.f));  // w-scale * h-scale
    #pragma unroll
    for (int t = 0; t < 4; ++t) {
      u32 pk[4];
      #pragma unroll
      for (int c4 = 0; c4 < 4; ++c4) {
        float4 f = *(const float4*)(wr + 64 * t + 4 * c4);
        pk[c4] = packq((int)rintf(f.x * qs), (int)rintf(f.y * qs),
                       (int)rintf(f.z * qs), (int)rintf(f.w * qs));
      }
      v4i v; v[0] = (int)pk[0]; v[1] = (int)pk[1]; v[2] = (int)pk[2]; v[3] = (int)pk[3];
      wfrag[m][t] = v;
    }
  }

  // act mapping: sel = mr&7 -> hb = sel&1, rg = sel>>1;
  // output d = 32w + 16*hb + 4q + rg. Lanes mr and mr+8 duplicate (only
  // mr<8 writes). Coverage per wave: exactly d in [32w, 32w+32).
  const int sel = mr & 7;
  const int hb = sel & 1, rg = sel >> 1;
  const int d = 32 * w + 16 * hb + 4 * q + rg;

  float creg = c0[dir * 256 + d];               // duplicated lanes identical
  if (mr < 8) {
    float hv = h0[dir * 256 + d];
    int qq = max(-127, min(127, (int)rintf(hv * 32.f)));
    hq8[0][d] = (char)qq;
  }
  __syncthreads();                              // init: full drain once

  const float fs0 = fsh[d],       fs1 = fsh[256 + d];
  const float fs2 = fsh[512 + d], fs3 = fsh[768 + d];
  const uint2* Gx2 = (const uint2*)Gx;
  uint2 ga[8];
  #pragma unroll
  for (int k = 0; k < 8; ++k) {
    const int t = dir ? (T_LEN - 1 - k) : k;
    ga[k] = Gx2[(size_t)t * 512 + dir * 256 + d];
  }

  for (int sb = 0; sb < T_LEN; sb += 8) {
    uint2 gn[8];
    const bool more = (sb + 8) < T_LEN;
    if (more) {          // prefetch next batch; rides across barriers
      #pragma unroll
      for (int k = 0; k < 8; ++k) {
        const int t2 = sb + 8 + k;
        const int t = dir ? (T_LEN - 1 - t2) : t2;
        gn[k] = Gx2[(size_t)t * 512 + dir * 256 + d];
      }
    }
    #pragma unroll
    for (int k = 0; k < 8; ++k) {
      const int s = sb + k;
      const char* hc = hq8[s & 1];
      v4i bfr[4];
      #pragma unroll
      for (int t = 0; t < 4; ++t)
        bfr[t] = *(const v4i*)(hc + 64 * t + 16 * q);
      v4i acc[8];
      #pragma unroll
      for (int m = 0; m < 8; ++m) {
        v4i a; a[0] = 0; a[1] = 0; a[2] = 0; a[3] = 0;
        a = __builtin_amdgcn_mfma_i32_16x16x64_i8(wfrag[m][0], bfr[0], a, 0, 0, 0);
        a = __builtin_amdgcn_mfma_i32_16x16x64_i8(wfrag[m][1], bfr[1], a, 0, 0, 0);
        a = __builtin_amdgcn_mfma_i32_16x16x64_i8(wfrag[m][2], bfr[2], a, 0, 0, 0);
        a = __builtin_amdgcn_mfma_i32_16x16x64_i8(wfrag[m][3], bfr[3], a, 0, 0, 0);
        acc[m] = a;
      }
      // ---- in-register gate extraction (7 cndmask per gate) ----
      // gate g for output d: tile g (hb=0) or 4+g (hb=1), C-row 4q+rg ->
      // element rg of that lane's acc (C cols identical, see header).
      int ri, rf, rgv, ro;
      {
        v4i lo, hi; int a01, a23, av, b01, b23, bv;
        lo = acc[0]; hi = acc[4];
        a01 = (rg & 1) ? lo[1] : lo[0]; a23 = (rg & 1) ? lo[3] : lo[2];
        av  = (rg & 2) ? a23 : a01;
        b01 = (rg & 1) ? hi[1] : hi[0]; b23 = (rg & 1) ? hi[3] : hi[2];
        bv  = (rg & 2) ? b23 : b01;
        ri = hb ? bv : av;
        lo = acc[1]; hi = acc[5];
        a01 = (rg & 1) ? lo[1] : lo[0]; a23 = (rg & 1) ? lo[3] : lo[2];
        av  = (rg & 2) ? a23 : a01;
        b01 = (rg & 1) ? hi[1] : hi[0]; b23 = (rg & 1) ? hi[3] : hi[2];
        bv  = (rg & 2) ? b23 : b01;
        rf = hb ? bv : av;
        lo = acc[2]; hi = acc[6];
        a01 = (rg & 1) ? lo[1] : lo[0]; a23 = (rg & 1) ? lo[3] : lo[2];
        av  = (rg & 2) ? a23 : a01;
        b01 = (rg & 1) ? hi[1] : hi[0]; b23 = (rg & 1) ? hi[3] : hi[2];
        bv  = (rg & 2) ? b23 : b01;
        rgv = hb ? bv : av;
        lo = acc[3]; hi = acc[7];
        a01 = (rg & 1) ? lo[1] : lo[0]; a23 = (rg & 1) ? lo[3] : lo[2];
        av  = (rg & 2) ? a23 : a01;
        b01 = (rg & 1) ? hi[1] : hi[0]; b23 = (rg & 1) ? hi[3] : hi[2];
        bv  = (rg & 2) ? b23 : b01;
        ro = hb ? bv : av;
      }
      // ---- activation (all lanes; duplicated lanes identical) ----
      const float xi = (float)ri  * fs0 + __half2float(__ushort_as_half((u16)(ga[k].x & 0xffff)));
      const float xf = (float)rf  * fs1 + __half2float(__ushort_as_half((u16)(ga[k].x >> 16)));
      const float xg = (float)rgv * fs2 + __half2float(__ushort_as_half((u16)(ga[k].y & 0xffff)));
      const float xo = (float)ro  * fs3 + __half2float(__ushort_as_half((u16)(ga[k].y >> 16)));
      const float iv = sigm(xi);
      const float fv = sigm(xf);
      const float gv = tanh_fast(xg);
      const float ov = sigm(xo);
      creg = __builtin_fmaf(fv, creg, iv * gv);
      const float h = ov * tanh_fast(creg);
      if (mr < 8) {
        int qq = max(-127, min(127, (int)rintf(h * 32.f)));
        hq8[(s + 1) & 1][d] = (char)qq;
        // direct coalesced store (fp16 round-trip keeps output
        // bit-identical to the old hist path); never waited on.
        const int tg = dir ? (T_LEN - 1 - s) : s;
        out_lstm[(size_t)tg * 512 + dir * 256 + d] =
            __half2float(__float2half(h));
      }
      wg_barrier();         // ONE barrier/step: h(s+1) published
    }
    if (more) {
      #pragma unroll
      for (int k = 0; k < 8; ++k) ga[k] = gn[k];
    }
  }
}

// ---------------------------------------------------------------------------
__global__ __launch_bounds__(256) void attn_kernel(
    const float* __restrict__ out_lstm, const float* __restrict__ w_omega,
    const float* __restrict__ u_omega, float* __restrict__ logits)
{
  __shared__ float bst[32][132];
  const int c0 = blockIdx.x * 32;
  const int t0 = blockIdx.y * 32;
  const int tid = threadIdx.x;
  const int ttb = tid >> 4, cgb = tid & 15;
  const float* a0p = out_lstm + (size_t)(t0 + ttb) * 512;
  const float* a1p = out_lstm + (size_t)(t0 + ttb + 16) * 512;
  float acc00 = 0, acc01 = 0, acc10 = 0, acc11 = 0;
  for (int kh = 0; kh < 4; ++kh) {
    __syncthreads();
    {
      const int cc = tid & 31;
      const int kA = tid >> 5;
      #pragma unroll
      for (int p = 0; p < 16; ++p) {
        const int kkx = kA + p * 8;
        bst[cc][kkx] = w_omega[(size_t)(kh * 128 + kkx) * 512 + c0 + cc];
      }
    }
    __syncthreads();
    #pragma unroll 4
    for (int k4 = 0; k4 < 128; k4 += 4) {
      float4 a0 = *(const float4*)(a0p + kh * 128 + k4);
      float4 a1 = *(const float4*)(a1p + kh * 128 + k4);
      float4 b0 = *(const float4*)&bst[cgb][k4];
      float4 b1 = *(const float4*)&bst[cgb + 16][k4];
      acc00 += a0.x*b0.x + a0.y*b0.y + a0.z*b0.z + a0.w*b0.w;
      acc01 += a0.x*b1.x + a0.y*b1.y + a0.z*b1.z + a0.w*b1.w;
      acc10 += a1.x*b0.x + a1.y*b0.y + a1.z*b0.z + a1.w*b0.w;
      acc11 += a1.x*b1.x + a1.y*b1.y + a1.z*b1.z + a1.w*b1.w;
    }
  }
  const float u0 = u_omega[c0 + cgb], u1 = u_omega[c0 + 16 + cgb];
  float s0 = tanh_fast(acc00) * u0 + tanh_fast(acc01) * u1;
  float s1 = tanh_fast(acc10) * u0 + tanh_fast(acc11) * u1;
  #pragma unroll
  for (int msk = 1; msk < 16; msk <<= 1) {
    s0 += __shfl_xor(s0, msk);
    s1 += __shfl_xor(s1, msk);
  }
  if (cgb == 0) {
    atomicAdd(&logits[t0 + ttb], s0);
    atomicAdd(&logits[t0 + ttb + 16], s1);
  }
}

// ---------------------------------------------------------------------------
__global__ __launch_bounds__(1024) void softmax_kernel(
    const float* __restrict__ logits, float* __restrict__ alphas)
{
  __shared__ float red[1024];
  const int tid = threadIdx.x;
  float l0 = logits[tid], l1 = logits[1024 + tid];
  float l2 = logits[2048 + tid], l3 = logits[3072 + tid];
  red[tid] = fmaxf(fmaxf(l0, l1), fmaxf(l2, l3));
  __syncthreads();
  for (int s = 512; s > 0; s >>= 1) {
    if (tid < s) red[tid] = fmaxf(red[tid], red[tid + s]);
    __syncthreads();
  }
  const float gm = red[0];
  __syncthreads();
  float e0 = __expf(l0 - gm), e1 = __expf(l1 - gm);
  float e2 = __expf(l2 - gm), e3 = __expf(l3 - gm);
  red[tid] = e0 + e1 + e2 + e3;
  __syncthreads();
  for (int s = 512; s > 0; s >>= 1) {
    if (tid < s) red[tid] += red[tid + s];
    __syncthreads();
  }
  const float inv = 1.0f / red[0];
  alphas[tid] = e0 * inv; alphas[1024 + tid] = e1 * inv;
  alphas[2048 + tid] = e2 * inv; alphas[3072 + tid] = e3 * inv;
}

// ---------------------------------------------------------------------------
__global__ __launch_bounds__(256) void feats_kernel(
    const float* __restrict__ out_lstm, const float* __restrict__ W_tag,
    const float* __restrict__ b_tag, const float* __restrict__ alphas,
    float* __restrict__ feats)
{
  __shared__ float wt[16][516];
  const int t0 = blockIdx.x * 16;
  const int tid = threadIdx.x;
  {
    const int k4 = (tid & 127) * 4;
    const int gA = tid >> 7;
    #pragma unroll
    for (int p = 0; p < 8; ++p) {
      const int tg = gA + p * 2;
      *(float4*)&wt[tg][k4] = *(const float4*)(W_tag + (size_t)tg * 512 + k4);
    }
  }
  __syncthreads();
  const int tt = tid >> 4, tg = tid & 15;
  const float* ap = out_lstm + (size_t)(t0 + tt) * 512;
  float acc = 0.f;
  #pragma unroll 4
  for (int k4 = 0; k4 < 512; k4 += 4) {
    float4 a = *(const float4*)(ap + k4);
    float4 b = *(const float4*)&wt[tg][k4];
    acc += a.x*b.x + a.y*b.y + a.z*b.z + a.w*b.w;
  }
  feats[(size_t)(t0 + tt) * 16 + tg] = acc * alphas[t0 + tt] + b_tag[tg];
}

// ---------------------------------------------------------------------------
__global__ __launch_bounds__(256) void vit_block_mats(
    const float* __restrict__ feats, const float* __restrict__ trans,
    float* __restrict__ Cmat)
{
  __shared__ float C[2][16][17];
  const int b = blockIdx.x;
  const int tid = threadIdx.x;
  const int n = tid >> 4, p = tid & 15;
  float tr[16];
  #pragma unroll
  for (int k = 0; k < 16; ++k) tr[k] = trans[n * 16 + k];
  const int t0 = b * 32;
  C[0][n][p] = tr[p] + feats[t0 * 16 + n];
  float fnext = feats[(t0 + 1) * 16 + n];
  __syncthreads();
  for (int s = 1; s < 32; ++s) {
    const float ft = fnext;
    if (s + 1 < 32) fnext = feats[(t0 + s + 1) * 16 + n];
    const int pr = (s - 1) & 1, cu = s & 1;
    float m = tr[0] + C[pr][0][p];
    #pragma unroll
    for (int k = 1; k < 16; ++k) m = fmaxf(m, tr[k] + C[pr][k][p]);
    C[cu][n][p] = m + ft;
    __syncthreads();
  }
  Cmat[b * 256 + n * 16 + p] = C[1][n][p];
}

__global__ __launch_bounds__(64) void vit_scan(
    const float* __restrict__ Cmat, const float* __restrict__ trans,
    float* __restrict__ v_in, float* __restrict__ d_out, u32* __restrict__ best_ws)
{
  const int l = threadIdx.x;
  const int n = l & 15, pg = l >> 4;
  float v = (n == START_TAG) ? 0.f : NEG_VAL;
  for (int b = 0; b < 128; ++b) {
    if (pg == 0) v_in[b * 16 + n] = v;
    float4 c4 = *(const float4*)&Cmat[b * 256 + n * 16 + pg * 4];
    float cand = c4.x + __shfl(v, pg * 4 + 0);
    cand = fmaxf(cand, c4.y + __shfl(v, pg * 4 + 1));
    cand = fmaxf(cand, c4.z + __shfl(v, pg * 4 + 2));
    cand = fmaxf(cand, c4.w + __shfl(v, pg * 4 + 3));
    cand = fmaxf(cand, __shfl_xor(cand, 16));
    cand = fmaxf(cand, __shfl_xor(cand, 32));
    v = cand;
  }
  float term = v + trans[STOP_TAG * 16 + n];
  int mi = n;
  #pragma unroll
  for (int msk = 1; msk < 16; msk <<= 1) {
    float om = __shfl_xor(term, msk); int omi = __shfl_xor(mi, msk);
    if (om > term || (om == term && omi < mi)) { term = om; mi = omi; }
  }
  if (l == 0) { d_out[0] = term; *best_ws = (u32)mi; }
}

__global__ __launch_bounds__(64) void vit_bp(
    const float* __restrict__ feats, const float* __restrict__ trans,
    const float* __restrict__ v_in, u32* __restrict__ bp)
{
  const int b = blockIdx.x;
  const int l = threadIdx.x;
  const int n = l & 15, pg = l >> 4;
  const float4 tr4 = *(const float4*)&trans[n * 16 + pg * 4];
  float v = v_in[b * 16 + n];
  const int t0 = b * 32;
  float fcur = feats[t0 * 16 + n];
  for (int s = 0; s < 32; ++s) {
    const int t = t0 + s;
    float fnext = (s + 1 < 32) ? feats[(t + 1) * 16 + n] : 0.f;
    float f0 = __shfl(v, pg * 4 + 0), f1 = __shfl(v, pg * 4 + 1);
    float f2 = __shfl(v, pg * 4 + 2), f3 = __shfl(v, pg * 4 + 3);
    float m = f0 + tr4.x; int mi = pg * 4;
    float c;
    c = f1 + tr4.y; if (c > m) { m = c; mi = pg * 4 + 1; }
    c = f2 + tr4.z; if (c > m) { m = c; mi = pg * 4 + 2; }
    c = f3 + tr4.w; if (c > m) { m = c; mi = pg * 4 + 3; }
    float om; int omi;
    om = __shfl_xor(m, 16); omi = __shfl_xor(mi, 16);
    if (om > m || (om == m && omi < mi)) { m = om; mi = omi; }
    om = __shfl_xor(m, 32); omi = __shfl_xor(mi, 32);
    if (om > m || (om == m && omi < mi)) { m = om; mi = omi; }
    u32 w = (l < 16) ? ((u32)mi << ((n & 7) * 4)) : 0u;
    w |= __shfl_xor(w, 1); w |= __shfl_xor(w, 2); w |= __shfl_xor(w, 4);
    if (l == 0) bp[t * 2] = w;
    if (l == 8) bp[t * 2 + 1] = w;
    v = m + fcur;
    fcur = fnext;
  }
}

__global__ __launch_bounds__(64) void vit_bmap(
    const u32* __restrict__ bp, u32* __restrict__ Bmap)
{
  const int b = blockIdx.x;
  const int l = threadIdx.x;
  if (l >= 16) return;
  int t = b * 32 + 31;
  u32 lo = bp[t * 2], hi = bp[t * 2 + 1];
  int A = (int)(((l < 8 ? lo : hi) >> ((l & 7) * 4)) & 15u);
  for (t = b * 32 + 30; t >= b * 32; --t) {
    lo = bp[t * 2]; hi = bp[t * 2 + 1];
    A = (int)(((A < 8 ? lo : hi) >> ((A & 7) * 4)) & 15u);
  }
  Bmap[b * 16 + l] = (u32)A;
}

__global__ __launch_bounds__(64) void vit_suffix(
    const u32* __restrict__ Bmap, u32* __restrict__ Stail)
{
  __shared__ u32 bm[2048];
  const int l = threadIdx.x;
  for (int i = l; i < 2048; i += 64) bm[i] = Bmap[i];
  __syncthreads();
  if (l < 16) {
    int S = l;
    for (int b = 127; b >= 0; --b) {
      Stail[b * 16 + l] = (u32)S;
      S = (int)bm[b * 16 + S];
    }
  }
}

__global__ __launch_bounds__(64) void vit_emit(
    const u32* __restrict__ bp, const u32* __restrict__ Stail,
    const u32* __restrict__ best_ws, float* __restrict__ d_out)
{
  const int b = blockIdx.x;
  const int l = threadIdx.x;
  const int best = (int)*best_ws;
  int A = (l < 16) ? (int)Stail[b * 16 + l] : 0;
  for (int s = 31; s >= 0; --s) {
    const int t = b * 32 + s;
    const int pv = __shfl(A, best);
    if (l == 0) d_out[1 + t] = (float)pv;
    if (s > 0) {
      const u32 lo = bp[t * 2], hi = bp[t * 2 + 1];
      A = (int)(((A < 8 ? lo : hi) >> ((A & 7) * 4)) & 15u);
    }
  }
}

// ---------------------------------------------------------------------------
extern "C" void kernel_launch(void* const* d_in, const int* in_sizes, int n_in,
                              void* d_out, int out_size, void* d_ws, size_t ws_size,
                              hipStream_t stream)
{
  const int*   sentence = (const int*)  d_in[0];
  const float* emb      = (const float*)d_in[1];
  const float* Wih_f    = (const float*)d_in[2];
  const float* Whh_f    = (const float*)d_in[3];
  const float* bih_f    = (const float*)d_in[4];
  const float* bhh_f    = (const float*)d_in[5];
  const float* Wih_b    = (const float*)d_in[6];
  const float* Whh_b    = (const float*)d_in[7];
  const float* bih_b    = (const float*)d_in[8];
  const float* bhh_b    = (const float*)d_in[9];
  const float* h0       = (const float*)d_in[10];
  const float* c0       = (const float*)d_in[11];
  const float* w_omega  = (const float*)d_in[12];
  const float* u_omega  = (const float*)d_in[13];
  const float* W_tag    = (const float*)d_in[14];
  const float* b_tag    = (const float*)d_in[15];
  const float* trans    = (const float*)d_in[16];

  char* ws = (char*)d_ws;
  __half* Gx      = (__half*)(ws + GX_OFF);
  float* out_lstm = (float*)(ws + OUT_OFF);
  float* logits   = (float*)(ws + LOGITS_OFF);
  float* alphas   = (float*)(ws + ALPHAS_OFF);
  float* feats    = (float*)(ws + FEATS_OFF);
  float* Cmat     = (float*)(ws + CMAT_OFF);
  float* v_in     = (float*)(ws + VIN_OFF);
  u32*   bp       = (u32*)  (ws + BP_OFF);
  u32*   Bmap     = (u32*)  (ws + BMAP_OFF);
  u32*   Stail    = (u32*)  (ws + STAIL_OFF);
  u32*   best_ws  = (u32*)  (ws + BEST_OFF);
  float* out      = (float*)d_out;

  hipLaunchKernelGGL(prep_kernel, dim3(4), dim3(1024), 0, stream, logits);
  hipLaunchKernelGGL(gx_kernel, dim3(64, 128), dim3(256), 0, stream,
                     sentence, emb, Wih_f, Wih_b, bih_f, bhh_f, bih_b, bhh_b, Gx);
  hipLaunchKernelGGL(lstm_kernel, dim3(2), dim3(512), 0, stream,
                     Whh_f, Whh_b, h0, c0, Gx, out_lstm);
  hipLaunchKernelGGL(attn_kernel, dim3(16, 128), dim3(256), 0, stream,
                     out_lstm, w_omega, u_omega, logits);
  hipLaunchKernelGGL(softmax_kernel, dim3(1), dim3(1024), 0, stream, logits, alphas);
  hipLaunchKernelGGL(feats_kernel, dim3(256), dim3(256), 0, stream,
                     out_lstm, W_tag, b_tag, alphas, feats);
  hipLaunchKernelGGL(vit_block_mats, dim3(128), dim3(256), 0, stream,
                     feats, trans, Cmat);
  hipLaunchKernelGGL(vit_scan, dim3(1), dim3(64), 0, stream,
                     Cmat, trans, v_in, out, best_ws);
  hipLaunchKernelGGL(vit_bp, dim3(128), dim3(64), 0, stream,
                     feats, trans, v_in, bp);
  hipLaunchKernelGGL(vit_bmap, dim3(128), dim3(64), 0, stream, bp, Bmap);
  hipLaunchKernelGGL(vit_suffix, dim3(1), dim3(64), 0, stream, Bmap, Stail);
  hipLaunchKernelGGL(vit_emit, dim3(128), dim3(64), 0, stream,
                     bp, Stail, best_ws, out);
}

// Round 12
// 3393.635 us; speedup vs baseline: 1.6355x; 1.0421x over previous
//
#include <hip/hip_runtime.h>
#include <hip/hip_fp16.h>

#define T_LEN 4096
#define START_TAG 14
#define STOP_TAG 15
#define NEG_VAL -10000.0f

typedef unsigned int u32;
typedef unsigned short u16;
typedef unsigned long long u64;
typedef int v4i __attribute__((ext_vector_type(4)));

// ---------- ws layout (bytes) ----------
#define GX_OFF      0u              // __half [4096][2048]  (dir*1024 + d*4 + gate)
#define OUT_OFF     16777216u       // float  [4096][512]
#define LOGITS_OFF  25165824u       // float  [4096]
#define ALPHAS_OFF  25182208u       // float  [4096]
#define FEATS_OFF   25198592u       // float  [4096][16]
#define CMAT_OFF    25460736u       // float  [128][16][16]
#define VIN_OFF     25591808u       // float  [128][16]
#define BP_OFF      25600000u       // u32    [4096][2]
#define BMAP_OFF    25632768u       // u32    [128][16]
#define STAIL_OFF   25640960u       // u32    [128][16]
#define BEST_OFF    25649152u       // u32    [1]

__device__ __forceinline__ u32 packq(int q0, int q1, int q2, int q3) {
  return (u32)(q0 & 255) | ((u32)(q1 & 255) << 8) |
         ((u32)(q2 & 255) << 16) | ((u32)(q3 & 255) << 24);
}

__device__ __forceinline__ float sigm(float x) {
  return __builtin_amdgcn_rcpf(1.f + __expf(-x));
}
__device__ __forceinline__ float tanh_fast(float x) {
  float e = __expf(-2.f * fabsf(x));
  float r = (1.f - e) * __builtin_amdgcn_rcpf(1.f + e);
  return copysignf(r, x);
}

// raw workgroup barrier: LDS visibility only (lgkmcnt), NO vmcnt drain --
// keeps the register Gx prefetch and the out_lstm stores in flight
// across barriers (m201 pattern).
__device__ __forceinline__ void wg_barrier() {
  asm volatile("s_waitcnt lgkmcnt(0)" ::: "memory");
  __builtin_amdgcn_s_barrier();
  __builtin_amdgcn_sched_barrier(0);
}

// ---------------------------------------------------------------------------
__global__ void prep_kernel(float* logits) {
  const int i = threadIdx.x + blockIdx.x * 1024;
  if (i < 4096) logits[i] = 0.f;
}

// ---------------------------------------------------------------------------
// Gx[t][dir*1024 + d*4 + gate] = emb[sentence[t]] . W-row + bih + bhh
__global__ __launch_bounds__(256) void gx_kernel(
    const int* __restrict__ sentence, const float* __restrict__ emb,
    const float* __restrict__ Wih_f, const float* __restrict__ Wih_b,
    const float* __restrict__ bih_f, const float* __restrict__ bhh_f,
    const float* __restrict__ bih_b, const float* __restrict__ bhh_b,
    __half* __restrict__ Gx)
{
  __shared__ float ws[32][260];
  const int r0 = blockIdx.x * 32;
  const int t0 = blockIdx.y * 32;
  const int tid = threadIdx.x;
  {
    const int c4 = (tid & 63) * 4;
    const int rA = tid >> 6;
    #pragma unroll
    for (int p = 0; p < 8; ++p) {
      const int rr = rA + p * 4;
      const int R = r0 + rr;
      const float* src = (R < 1024) ? (Wih_f + (size_t)R * 256 + c4)
                                    : (Wih_b + (size_t)(R - 1024) * 256 + c4);
      *(float4*)&ws[rr][c4] = *(const float4*)src;
    }
  }
  __syncthreads();
  const int ttb = tid >> 4, rgb = tid & 15;
  const int s0r = sentence[t0 + ttb];
  const int s1r = sentence[t0 + ttb + 16];
  const float* x0p = emb + (size_t)s0r * 256;
  const float* x1p = emb + (size_t)s1r * 256;
  float acc00 = 0, acc01 = 0, acc10 = 0, acc11 = 0;
  #pragma unroll 4
  for (int c4 = 0; c4 < 256; c4 += 4) {
    float4 x0 = *(const float4*)(x0p + c4);
    float4 x1 = *(const float4*)(x1p + c4);
    float4 w0 = *(const float4*)&ws[rgb][c4];
    float4 w1 = *(const float4*)&ws[rgb + 16][c4];
    acc00 += x0.x*w0.x + x0.y*w0.y + x0.z*w0.z + x0.w*w0.w;
    acc01 += x0.x*w1.x + x0.y*w1.y + x0.z*w1.z + x0.w*w1.w;
    acc10 += x1.x*w0.x + x1.y*w0.y + x1.z*w0.z + x1.w*w0.w;
    acc11 += x1.x*w1.x + x1.y*w1.y + x1.z*w1.z + x1.w*w1.w;
  }
  #pragma unroll
  for (int ri = 0; ri < 2; ++ri) {
    const int R = r0 + rgb + ri * 16;
    const int dir = R >> 10, grow = R & 1023;
    const int gate = grow >> 8, dd = grow & 255;
    const float bias = dir ? (bih_b[grow] + bhh_b[grow])
                           : (bih_f[grow] + bhh_f[grow]);
    const float a0 = ri ? acc01 : acc00;
    const float a1 = ri ? acc11 : acc10;
    const size_t off = (size_t)dir * 1024 + dd * 4 + gate;
    Gx[(size_t)(t0 + ttb) * 2048 + off]      = __float2half(a0 + bias);
    Gx[(size_t)(t0 + ttb + 16) * 2048 + off] = __float2half(a1 + bias);
  }
}

// ---------------------------------------------------------------------------
// Recurrence v17 = v16 (best: 3078 us) + per-gate MFMA/act interleave +
// s_setprio. v16's skeleton unchanged: gate sums never touch LDS (all 16
// MFMA C-columns identical -> lane-held acc; cndmask extraction), ONE
// barrier/step, direct fire-and-forget out_lstm store. v17 reorders the
// step body into 4 gate-groups {tiles g,g+4 -> extract g -> activate g}
// so each gate's VALU/TRANS work overlaps the NEXT gate's MFMA issue;
// the post-last-MFMA serial tail shrinks from ~200 cyc (full 4-gate
// extract+act) to ~80 (o-gate only + cell chain). Same DAG, same float
// expression order -> output bit-identical. setprio(1) wraps the MFMA
// region (T5; likely small/null on lockstep waves, safe).
// (Round-11 bench was an infra failure -- "container failed twice" --
// so this is an unchanged resubmit of v17.)
__global__ __launch_bounds__(512, 2) void lstm_kernel(
    const float* __restrict__ Whh_f, const float* __restrict__ Whh_b,
    const float* __restrict__ h0, const float* __restrict__ c0,
    const __half* __restrict__ Gx, float* __restrict__ out_lstm)
{
  const int dir = blockIdx.x;
  const int tid = threadIdx.x;
  const int w = tid >> 6, l = tid & 63;
  const int mr = l & 15, q = l >> 4;
  const float* Whh = dir ? Whh_b : Whh_f;

  __shared__ __align__(16) char hq8[2][256];    // int8 h, parity buffers
  __shared__ float fsh[1024];                   // per-row scales (all gates)

  // ---- init: wave w, M-tile m -> gate g=m&3, half hb=m>>2,
  //      global row = g*256 + 32w + 16*hb + mr ----
  v4i wfrag[8][4];
  #pragma unroll
  for (int m = 0; m < 8; ++m) {
    const int row = (m & 3) * 256 + 32 * w + 16 * (m >> 2) + mr;
    const float* wr = Whh + (size_t)row * 256 + 16 * q;
    float mx = 1e-10f;
    #pragma unroll
    for (int t = 0; t < 4; ++t) {
      #pragma unroll
      for (int c4 = 0; c4 < 4; ++c4) {
        float4 f = *(const float4*)(wr + 64 * t + 4 * c4);
        mx = fmaxf(mx, fmaxf(fmaxf(fabsf(f.x), fabsf(f.y)),
                             fmaxf(fabsf(f.z), fabsf(f.w))));
      }
    }
    mx = fmaxf(mx, __shfl_xor(mx, 16));
    mx = fmaxf(mx, __shfl_xor(mx, 32));
    const float qs = 127.f / mx;
    if (q == 0) fsh[row] = mx * (1.f / (127.f * 32.f));  // w-scale * h-scale
    #pragma unroll
    for (int t = 0; t < 4; ++t) {
      u32 pk[4];
      #pragma unroll
      for (int c4 = 0; c4 < 4; ++c4) {
        float4 f = *(const float4*)(wr + 64 * t + 4 * c4);
        pk[c4] = packq((int)rintf(f.x * qs), (int)rintf(f.y * qs),
                       (int)rintf(f.z * qs), (int)rintf(f.w * qs));
      }
      v4i v; v[0] = (int)pk[0]; v[1] = (int)pk[1]; v[2] = (int)pk[2]; v[3] = (int)pk[3];
      wfrag[m][t] = v;
    }
  }

  // act mapping: sel = mr&7 -> hb = sel&1, rg = sel>>1;
  // output d = 32w + 16*hb + 4q + rg. Lanes mr and mr+8 duplicate (only
  // mr<8 writes). Coverage per wave: exactly d in [32w, 32w+32).
  const int sel = mr & 7;
  const int hb = sel & 1, rg = sel >> 1;
  const int d = 32 * w + 16 * hb + 4 * q + rg;

  float creg = c0[dir * 256 + d];               // duplicated lanes identical
  if (mr < 8) {
    float hv = h0[dir * 256 + d];
    int qq = max(-127, min(127, (int)rintf(hv * 32.f)));
    hq8[0][d] = (char)qq;
  }
  __syncthreads();                              // init: full drain once

  const float fs0 = fsh[d],       fs1 = fsh[256 + d];
  const float fs2 = fsh[512 + d], fs3 = fsh[768 + d];
  const uint2* Gx2 = (const uint2*)Gx;
  uint2 ga[8];
  #pragma unroll
  for (int k = 0; k < 8; ++k) {
    const int t = dir ? (T_LEN - 1 - k) : k;
    ga[k] = Gx2[(size_t)t * 512 + dir * 256 + d];
  }

  for (int sb = 0; sb < T_LEN; sb += 8) {
    uint2 gn[8];
    const bool more = (sb + 8) < T_LEN;
    if (more) {          // prefetch next batch; rides across barriers
      #pragma unroll
      for (int k = 0; k < 8; ++k) {
        const int t2 = sb + 8 + k;
        const int t = dir ? (T_LEN - 1 - t2) : t2;
        gn[k] = Gx2[(size_t)t * 512 + dir * 256 + d];
      }
    }
    #pragma unroll
    for (int k = 0; k < 8; ++k) {
      const int s = sb + k;
      const char* hc = hq8[s & 1];
      v4i bfr[4];
      #pragma unroll
      for (int t = 0; t < 4; ++t)
        bfr[t] = *(const v4i*)(hc + 64 * t + 16 * q);

      __builtin_amdgcn_s_setprio(1);
      // ---- gate i: tiles 0,4 -> extract -> sigmoid ----
      v4i aL, aH;
      aL[0]=0; aL[1]=0; aL[2]=0; aL[3]=0;
      aL = __builtin_amdgcn_mfma_i32_16x16x64_i8(wfrag[0][0], bfr[0], aL, 0, 0, 0);
      aL = __builtin_amdgcn_mfma_i32_16x16x64_i8(wfrag[0][1], bfr[1], aL, 0, 0, 0);
      aL = __builtin_amdgcn_mfma_i32_16x16x64_i8(wfrag[0][2], bfr[2], aL, 0, 0, 0);
      aL = __builtin_amdgcn_mfma_i32_16x16x64_i8(wfrag[0][3], bfr[3], aL, 0, 0, 0);
      aH[0]=0; aH[1]=0; aH[2]=0; aH[3]=0;
      aH = __builtin_amdgcn_mfma_i32_16x16x64_i8(wfrag[4][0], bfr[0], aH, 0, 0, 0);
      aH = __builtin_amdgcn_mfma_i32_16x16x64_i8(wfrag[4][1], bfr[1], aH, 0, 0, 0);
      aH = __builtin_amdgcn_mfma_i32_16x16x64_i8(wfrag[4][2], bfr[2], aH, 0, 0, 0);
      aH = __builtin_amdgcn_mfma_i32_16x16x64_i8(wfrag[4][3], bfr[3], aH, 0, 0, 0);
      int a01, a23, av, b01, b23, bv;
      a01 = (rg & 1) ? aL[1] : aL[0]; a23 = (rg & 1) ? aL[3] : aL[2];
      av  = (rg & 2) ? a23 : a01;
      b01 = (rg & 1) ? aH[1] : aH[0]; b23 = (rg & 1) ? aH[3] : aH[2];
      bv  = (rg & 2) ? b23 : b01;
      const int ri = hb ? bv : av;
      const float xi = (float)ri * fs0 + __half2float(__ushort_as_half((u16)(ga[k].x & 0xffff)));
      const float iv = sigm(xi);

      // ---- gate f: tiles 1,5 ----
      aL[0]=0; aL[1]=0; aL[2]=0; aL[3]=0;
      aL = __builtin_amdgcn_mfma_i32_16x16x64_i8(wfrag[1][0], bfr[0], aL, 0, 0, 0);
      aL = __builtin_amdgcn_mfma_i32_16x16x64_i8(wfrag[1][1], bfr[1], aL, 0, 0, 0);
      aL = __builtin_amdgcn_mfma_i32_16x16x64_i8(wfrag[1][2], bfr[2], aL, 0, 0, 0);
      aL = __builtin_amdgcn_mfma_i32_16x16x64_i8(wfrag[1][3], bfr[3], aL, 0, 0, 0);
      aH[0]=0; aH[1]=0; aH[2]=0; aH[3]=0;
      aH = __builtin_amdgcn_mfma_i32_16x16x64_i8(wfrag[5][0], bfr[0], aH, 0, 0, 0);
      aH = __builtin_amdgcn_mfma_i32_16x16x64_i8(wfrag[5][1], bfr[1], aH, 0, 0, 0);
      aH = __builtin_amdgcn_mfma_i32_16x16x64_i8(wfrag[5][2], bfr[2], aH, 0, 0, 0);
      aH = __builtin_amdgcn_mfma_i32_16x16x64_i8(wfrag[5][3], bfr[3], aH, 0, 0, 0);
      a01 = (rg & 1) ? aL[1] : aL[0]; a23 = (rg & 1) ? aL[3] : aL[2];
      av  = (rg & 2) ? a23 : a01;
      b01 = (rg & 1) ? aH[1] : aH[0]; b23 = (rg & 1) ? aH[3] : aH[2];
      bv  = (rg & 2) ? b23 : b01;
      const int rf = hb ? bv : av;
      const float xf = (float)rf * fs1 + __half2float(__ushort_as_half((u16)(ga[k].x >> 16)));
      const float fv = sigm(xf);

      // ---- gate g: tiles 2,6 ----
      aL[0]=0; aL[1]=0; aL[2]=0; aL[3]=0;
      aL = __builtin_amdgcn_mfma_i32_16x16x64_i8(wfrag[2][0], bfr[0], aL, 0, 0, 0);
      aL = __builtin_amdgcn_mfma_i32_16x16x64_i8(wfrag[2][1], bfr[1], aL, 0, 0, 0);
      aL = __builtin_amdgcn_mfma_i32_16x16x64_i8(wfrag[2][2], bfr[2], aL, 0, 0, 0);
      aL = __builtin_amdgcn_mfma_i32_16x16x64_i8(wfrag[2][3], bfr[3], aL, 0, 0, 0);
      aH[0]=0; aH[1]=0; aH[2]=0; aH[3]=0;
      aH = __builtin_amdgcn_mfma_i32_16x16x64_i8(wfrag[6][0], bfr[0], aH, 0, 0, 0);
      aH = __builtin_amdgcn_mfma_i32_16x16x64_i8(wfrag[6][1], bfr[1], aH, 0, 0, 0);
      aH = __builtin_amdgcn_mfma_i32_16x16x64_i8(wfrag[6][2], bfr[2], aH, 0, 0, 0);
      aH = __builtin_amdgcn_mfma_i32_16x16x64_i8(wfrag[6][3], bfr[3], aH, 0, 0, 0);
      a01 = (rg & 1) ? aL[1] : aL[0]; a23 = (rg & 1) ? aL[3] : aL[2];
      av  = (rg & 2) ? a23 : a01;
      b01 = (rg & 1) ? aH[1] : aH[0]; b23 = (rg & 1) ? aH[3] : aH[2];
      bv  = (rg & 2) ? b23 : b01;
      const int rgv = hb ? bv : av;
      const float xg = (float)rgv * fs2 + __half2float(__ushort_as_half((u16)(ga[k].y & 0xffff)));
      const float gv = tanh_fast(xg);

      // ---- gate o: tiles 3,7 ----
      aL[0]=0; aL[1]=0; aL[2]=0; aL[3]=0;
      aL = __builtin_amdgcn_mfma_i32_16x16x64_i8(wfrag[3][0], bfr[0], aL, 0, 0, 0);
      aL = __builtin_amdgcn_mfma_i32_16x16x64_i8(wfrag[3][1], bfr[1], aL, 0, 0, 0);
      aL = __builtin_amdgcn_mfma_i32_16x16x64_i8(wfrag[3][2], bfr[2], aL, 0, 0, 0);
      aL = __builtin_amdgcn_mfma_i32_16x16x64_i8(wfrag[3][3], bfr[3], aL, 0, 0, 0);
      aH[0]=0; aH[1]=0; aH[2]=0; aH[3]=0;
      aH = __builtin_amdgcn_mfma_i32_16x16x64_i8(wfrag[7][0], bfr[0], aH, 0, 0, 0);
      aH = __builtin_amdgcn_mfma_i32_16x16x64_i8(wfrag[7][1], bfr[1], aH, 0, 0, 0);
      aH = __builtin_amdgcn_mfma_i32_16x16x64_i8(wfrag[7][2], bfr[2], aH, 0, 0, 0);
      aH = __builtin_amdgcn_mfma_i32_16x16x64_i8(wfrag[7][3], bfr[3], aH, 0, 0, 0);
      __builtin_amdgcn_s_setprio(0);
      a01 = (rg & 1) ? aL[1] : aL[0]; a23 = (rg & 1) ? aL[3] : aL[2];
      av  = (rg & 2) ? a23 : a01;
      b01 = (rg & 1) ? aH[1] : aH[0]; b23 = (rg & 1) ? aH[3] : aH[2];
      bv  = (rg & 2) ? b23 : b01;
      const int ro = hb ? bv : av;
      const float xo = (float)ro * fs3 + __half2float(__ushort_as_half((u16)(ga[k].y >> 16)));
      const float ov = sigm(xo);

      // ---- cell update (all lanes; duplicated lanes identical) ----
      creg = __builtin_fmaf(fv, creg, iv * gv);
      const float h = ov * tanh_fast(creg);
      if (mr < 8) {
        int qq = max(-127, min(127, (int)rintf(h * 32.f)));
        hq8[(s + 1) & 1][d] = (char)qq;
        // direct coalesced store (fp16 round-trip keeps output
        // bit-identical to the old hist path); never waited on.
        const int tg = dir ? (T_LEN - 1 - s) : s;
        out_lstm[(size_t)tg * 512 + dir * 256 + d] =
            __half2float(__float2half(h));
      }
      wg_barrier();         // ONE barrier/step: h(s+1) published
    }
    if (more) {
      #pragma unroll
      for (int k = 0; k < 8; ++k) ga[k] = gn[k];
    }
  }
}

// ---------------------------------------------------------------------------
__global__ __launch_bounds__(256) void attn_kernel(
    const float* __restrict__ out_lstm, const float* __restrict__ w_omega,
    const float* __restrict__ u_omega, float* __restrict__ logits)
{
  __shared__ float bst[32][132];
  const int c0 = blockIdx.x * 32;
  const int t0 = blockIdx.y * 32;
  const int tid = threadIdx.x;
  const int ttb = tid >> 4, cgb = tid & 15;
  const float* a0p = out_lstm + (size_t)(t0 + ttb) * 512;
  const float* a1p = out_lstm + (size_t)(t0 + ttb + 16) * 512;
  float acc00 = 0, acc01 = 0, acc10 = 0, acc11 = 0;
  for (int kh = 0; kh < 4; ++kh) {
    __syncthreads();
    {
      const int cc = tid & 31;
      const int kA = tid >> 5;
      #pragma unroll
      for (int p = 0; p < 16; ++p) {
        const int kkx = kA + p * 8;
        bst[cc][kkx] = w_omega[(size_t)(kh * 128 + kkx) * 512 + c0 + cc];
      }
    }
    __syncthreads();
    #pragma unroll 4
    for (int k4 = 0; k4 < 128; k4 += 4) {
      float4 a0 = *(const float4*)(a0p + kh * 128 + k4);
      float4 a1 = *(const float4*)(a1p + kh * 128 + k4);
      float4 b0 = *(const float4*)&bst[cgb][k4];
      float4 b1 = *(const float4*)&bst[cgb + 16][k4];
      acc00 += a0.x*b0.x + a0.y*b0.y + a0.z*b0.z + a0.w*b0.w;
      acc01 += a0.x*b1.x + a0.y*b1.y + a0.z*b1.z + a0.w*b1.w;
      acc10 += a1.x*b0.x + a1.y*b0.y + a1.z*b0.z + a1.w*b0.w;
      acc11 += a1.x*b1.x + a1.y*b1.y + a1.z*b1.z + a1.w*b1.w;
    }
  }
  const float u0 = u_omega[c0 + cgb], u1 = u_omega[c0 + 16 + cgb];
  float s0 = tanh_fast(acc00) * u0 + tanh_fast(acc01) * u1;
  float s1 = tanh_fast(acc10) * u0 + tanh_fast(acc11) * u1;
  #pragma unroll
  for (int msk = 1; msk < 16; msk <<= 1) {
    s0 += __shfl_xor(s0, msk);
    s1 += __shfl_xor(s1, msk);
  }
  if (cgb == 0) {
    atomicAdd(&logits[t0 + ttb], s0);
    atomicAdd(&logits[t0 + ttb + 16], s1);
  }
}

// ---------------------------------------------------------------------------
__global__ __launch_bounds__(1024) void softmax_kernel(
    const float* __restrict__ logits, float* __restrict__ alphas)
{
  __shared__ float red[1024];
  const int tid = threadIdx.x;
  float l0 = logits[tid], l1 = logits[1024 + tid];
  float l2 = logits[2048 + tid], l3 = logits[3072 + tid];
  red[tid] = fmaxf(fmaxf(l0, l1), fmaxf(l2, l3));
  __syncthreads();
  for (int s = 512; s > 0; s >>= 1) {
    if (tid < s) red[tid] = fmaxf(red[tid], red[tid + s]);
    __syncthreads();
  }
  const float gm = red[0];
  __syncthreads();
  float e0 = __expf(l0 - gm), e1 = __expf(l1 - gm);
  float e2 = __expf(l2 - gm), e3 = __expf(l3 - gm);
  red[tid] = e0 + e1 + e2 + e3;
  __syncthreads();
  for (int s = 512; s > 0; s >>= 1) {
    if (tid < s) red[tid] += red[tid + s];
    __syncthreads();
  }
  const float inv = 1.0f / red[0];
  alphas[tid] = e0 * inv; alphas[1024 + tid] = e1 * inv;
  alphas[2048 + tid] = e2 * inv; alphas[3072 + tid] = e3 * inv;
}

// ---------------------------------------------------------------------------
__global__ __launch_bounds__(256) void feats_kernel(
    const float* __restrict__ out_lstm, const float* __restrict__ W_tag,
    const float* __restrict__ b_tag, const float* __restrict__ alphas,
    float* __restrict__ feats)
{
  __shared__ float wt[16][516];
  const int t0 = blockIdx.x * 16;
  const int tid = threadIdx.x;
  {
    const int k4 = (tid & 127) * 4;
    const int gA = tid >> 7;
    #pragma unroll
    for (int p = 0; p < 8; ++p) {
      const int tg = gA + p * 2;
      *(float4*)&wt[tg][k4] = *(const float4*)(W_tag + (size_t)tg * 512 + k4);
    }
  }
  __syncthreads();
  const int tt = tid >> 4, tg = tid & 15;
  const float* ap = out_lstm + (size_t)(t0 + tt) * 512;
  float acc = 0.f;
  #pragma unroll 4
  for (int k4 = 0; k4 < 512; k4 += 4) {
    float4 a = *(const float4*)(ap + k4);
    float4 b = *(const float4*)&wt[tg][k4];
    acc += a.x*b.x + a.y*b.y + a.z*b.z + a.w*b.w;
  }
  feats[(size_t)(t0 + tt) * 16 + tg] = acc * alphas[t0 + tt] + b_tag[tg];
}

// ---------------------------------------------------------------------------
__global__ __launch_bounds__(256) void vit_block_mats(
    const float* __restrict__ feats, const float* __restrict__ trans,
    float* __restrict__ Cmat)
{
  __shared__ float C[2][16][17];
  const int b = blockIdx.x;
  const int tid = threadIdx.x;
  const int n = tid >> 4, p = tid & 15;
  float tr[16];
  #pragma unroll
  for (int k = 0; k < 16; ++k) tr[k] = trans[n * 16 + k];
  const int t0 = b * 32;
  C[0][n][p] = tr[p] + feats[t0 * 16 + n];
  float fnext = feats[(t0 + 1) * 16 + n];
  __syncthreads();
  for (int s = 1; s < 32; ++s) {
    const float ft = fnext;
    if (s + 1 < 32) fnext = feats[(t0 + s + 1) * 16 + n];
    const int pr = (s - 1) & 1, cu = s & 1;
    float m = tr[0] + C[pr][0][p];
    #pragma unroll
    for (int k = 1; k < 16; ++k) m = fmaxf(m, tr[k] + C[pr][k][p]);
    C[cu][n][p] = m + ft;
    __syncthreads();
  }
  Cmat[b * 256 + n * 16 + p] = C[1][n][p];
}

__global__ __launch_bounds__(64) void vit_scan(
    const float* __restrict__ Cmat, const float* __restrict__ trans,
    float* __restrict__ v_in, float* __restrict__ d_out, u32* __restrict__ best_ws)
{
  const int l = threadIdx.x;
  const int n = l & 15, pg = l >> 4;
  float v = (n == START_TAG) ? 0.f : NEG_VAL;
  for (int b = 0; b < 128; ++b) {
    if (pg == 0) v_in[b * 16 + n] = v;
    float4 c4 = *(const float4*)&Cmat[b * 256 + n * 16 + pg * 4];
    float cand = c4.x + __shfl(v, pg * 4 + 0);
    cand = fmaxf(cand, c4.y + __shfl(v, pg * 4 + 1));
    cand = fmaxf(cand, c4.z + __shfl(v, pg * 4 + 2));
    cand = fmaxf(cand, c4.w + __shfl(v, pg * 4 + 3));
    cand = fmaxf(cand, __shfl_xor(cand, 16));
    cand = fmaxf(cand, __shfl_xor(cand, 32));
    v = cand;
  }
  float term = v + trans[STOP_TAG * 16 + n];
  int mi = n;
  #pragma unroll
  for (int msk = 1; msk < 16; msk <<= 1) {
    float om = __shfl_xor(term, msk); int omi = __shfl_xor(mi, msk);
    if (om > term || (om == term && omi < mi)) { term = om; mi = omi; }
  }
  if (l == 0) { d_out[0] = term; *best_ws = (u32)mi; }
}

__global__ __launch_bounds__(64) void vit_bp(
    const float* __restrict__ feats, const float* __restrict__ trans,
    const float* __restrict__ v_in, u32* __restrict__ bp)
{
  const int b = blockIdx.x;
  const int l = threadIdx.x;
  const int n = l & 15, pg = l >> 4;
  const float4 tr4 = *(const float4*)&trans[n * 16 + pg * 4];
  float v = v_in[b * 16 + n];
  const int t0 = b * 32;
  float fcur = feats[t0 * 16 + n];
  for (int s = 0; s < 32; ++s) {
    const int t = t0 + s;
    float fnext = (s + 1 < 32) ? feats[(t + 1) * 16 + n] : 0.f;
    float f0 = __shfl(v, pg * 4 + 0), f1 = __shfl(v, pg * 4 + 1);
    float f2 = __shfl(v, pg * 4 + 2), f3 = __shfl(v, pg * 4 + 3);
    float m = f0 + tr4.x; int mi = pg * 4;
    float c;
    c = f1 + tr4.y; if (c > m) { m = c; mi = pg * 4 + 1; }
    c = f2 + tr4.z; if (c > m) { m = c; mi = pg * 4 + 2; }
    c = f3 + tr4.w; if (c > m) { m = c; mi = pg * 4 + 3; }
    float om; int omi;
    om = __shfl_xor(m, 16); omi = __shfl_xor(mi, 16);
    if (om > m || (om == m && omi < mi)) { m = om; mi = omi; }
    om = __shfl_xor(m, 32); omi = __shfl_xor(mi, 32);
    if (om > m || (om == m && omi < mi)) { m = om; mi = omi; }
    u32 w = (l < 16) ? ((u32)mi << ((n & 7) * 4)) : 0u;
    w |= __shfl_xor(w, 1); w |= __shfl_xor(w, 2); w |= __shfl_xor(w, 4);
    if (l == 0) bp[t * 2] = w;
    if (l == 8) bp[t * 2 + 1] = w;
    v = m + fcur;
    fcur = fnext;
  }
}

__global__ __launch_bounds__(64) void vit_bmap(
    const u32* __restrict__ bp, u32* __restrict__ Bmap)
{
  const int b = blockIdx.x;
  const int l = threadIdx.x;
  if (l >= 16) return;
  int t = b * 32 + 31;
  u32 lo = bp[t * 2], hi = bp[t * 2 + 1];
  int A = (int)(((l < 8 ? lo : hi) >> ((l & 7) * 4)) & 15u);
  for (t = b * 32 + 30; t >= b * 32; --t) {
    lo = bp[t * 2]; hi = bp[t * 2 + 1];
    A = (int)(((A < 8 ? lo : hi) >> ((A & 7) * 4)) & 15u);
  }
  Bmap[b * 16 + l] = (u32)A;
}

__global__ __launch_bounds__(64) void vit_suffix(
    const u32* __restrict__ Bmap, u32* __restrict__ Stail)
{
  __shared__ u32 bm[2048];
  const int l = threadIdx.x;
  for (int i = l; i < 2048; i += 64) bm[i] = Bmap[i];
  __syncthreads();
  if (l < 16) {
    int S = l;
    for (int b = 127; b >= 0; --b) {
      Stail[b * 16 + l] = (u32)S;
      S = (int)bm[b * 16 + S];
    }
  }
}

__global__ __launch_bounds__(64) void vit_emit(
    const u32* __restrict__ bp, const u32* __restrict__ Stail,
    const u32* __restrict__ best_ws, float* __restrict__ d_out)
{
  const int b = blockIdx.x;
  const int l = threadIdx.x;
  const int best = (int)*best_ws;
  int A = (l < 16) ? (int)Stail[b * 16 + l] : 0;
  for (int s = 31; s >= 0; --s) {
    const int t = b * 32 + s;
    const int pv = __shfl(A, best);
    if (l == 0) d_out[1 + t] = (float)pv;
    if (s > 0) {
      const u32 lo = bp[t * 2], hi = bp[t * 2 + 1];
      A = (int)(((A < 8 ? lo : hi) >> ((A & 7) * 4)) & 15u);
    }
  }
}

// ---------------------------------------------------------------------------
extern "C" void kernel_launch(void* const* d_in, const int* in_sizes, int n_in,
                              void* d_out, int out_size, void* d_ws, size_t ws_size,
                              hipStream_t stream)
{
  const int*   sentence = (const int*)  d_in[0];
  const float* emb      = (const float*)d_in[1];
  const float* Wih_f    = (const float*)d_in[2];
  const float* Whh_f    = (const float*)d_in[3];
  const float* bih_f    = (const float*)d_in[4];
  const float* bhh_f    = (const float*)d_in[5];
  const float* Wih_b    = (const float*)d_in[6];
  const float* Whh_b    = (const float*)d_in[7];
  const float* bih_b    = (const float*)d_in[8];
  const float* bhh_b    = (const float*)d_in[9];
  const float* h0       = (const float*)d_in[10];
  const float* c0       = (const float*)d_in[11];
  const float* w_omega  = (const float*)d_in[12];
  const float* u_omega  = (const float*)d_in[13];
  const float* W_tag    = (const float*)d_in[14];
  const float* b_tag    = (const float*)d_in[15];
  const float* trans    = (const float*)d_in[16];

  char* ws = (char*)d_ws;
  __half* Gx      = (__half*)(ws + GX_OFF);
  float* out_lstm = (float*)(ws + OUT_OFF);
  float* logits   = (float*)(ws + LOGITS_OFF);
  float* alphas   = (float*)(ws + ALPHAS_OFF);
  float* feats    = (float*)(ws + FEATS_OFF);
  float* Cmat     = (float*)(ws + CMAT_OFF);
  float* v_in     = (float*)(ws + VIN_OFF);
  u32*   bp       = (u32*)  (ws + BP_OFF);
  u32*   Bmap     = (u32*)  (ws + BMAP_OFF);
  u32*   Stail    = (u32*)  (ws + STAIL_OFF);
  u32*   best_ws  = (u32*)  (ws + BEST_OFF);
  float* out      = (float*)d_out;

  hipLaunchKernelGGL(prep_kernel, dim3(4), dim3(1024), 0, stream, logits);
  hipLaunchKernelGGL(gx_kernel, dim3(64, 128), dim3(256), 0, stream,
                     sentence, emb, Wih_f, Wih_b, bih_f, bhh_f, bih_b, bhh_b, Gx);
  hipLaunchKernelGGL(lstm_kernel, dim3(2), dim3(512), 0, stream,
                     Whh_f, Whh_b, h0, c0, Gx, out_lstm);
  hipLaunchKernelGGL(attn_kernel, dim3(16, 128), dim3(256), 0, stream,
                     out_lstm, w_omega, u_omega, logits);
  hipLaunchKernelGGL(softmax_kernel, dim3(1), dim3(1024), 0, stream, logits, alphas);
  hipLaunchKernelGGL(feats_kernel, dim3(256), dim3(256), 0, stream,
                     out_lstm, W_tag, b_tag, alphas, feats);
  hipLaunchKernelGGL(vit_block_mats, dim3(128), dim3(256), 0, stream,
                     feats, trans, Cmat);
  hipLaunchKernelGGL(vit_scan, dim3(1), dim3(64), 0, stream,
                     Cmat, trans, v_in, out, best_ws);
  hipLaunchKernelGGL(vit_bp, dim3(128), dim3(64), 0, stream,
                     feats, trans, v_in, bp);
  hipLaunchKernelGGL(vit_bmap, dim3(128), dim3(64), 0, stream, bp, Bmap);
  hipLaunchKernelGGL(vit_suffix, dim3(1), dim3(64), 0, stream, Bmap, Stail);
  hipLaunchKernelGGL(vit_emit, dim3(128), dim3(64), 0, stream,
                     bp, Stail, best_ws, out);
}